// Round 1
// baseline (24875.084 us; speedup 1.0000x reference)
//
#include <hip/hip_runtime.h>
#include <math.h>

namespace {

constexpr int kN   = 10000;
constexpr int kE   = 200000;
constexpr int kLat = 128;
constexpr int kNT  = 95;
constexpr int kM0 = 128, kM1 = 64, kM2 = 32;
constexpr int kC0 = 192, kC1 = 96, kC2 = 48;
constexpr int kT0 = 224;
constexpr int kNFD = 480, kEFD = 240;
constexpr int kB = 16;       // edges per block
constexpr int kTPB = 512;

// shared-memory carve (float offsets); all regions [feature][edge] transposed
constexpr int OF_LAT = 0;                   // 128*16
constexpr int OF_X0  = OF_LAT + kLat*kB;    // 192*16
constexpr int OF_X1R = OF_X0 + kC0*kB;      // 288*16
constexpr int OF_X2R = OF_X1R + kC1*3*kB;   // 240*16
constexpr int OF_S   = OF_X2R + kC2*5*kB;   // 128*16  silu(t0[:128])
constexpr int OF_T0G = OF_S + kM0*kB;       // 96*16   sigmoid(t0[128:224])
constexpr int OF_Y1  = OF_T0G + 96*kB;      // 192*16
constexpr int OF_Y2  = OF_Y1 + kM1*3*kB;    // 160*16
constexpr int OF_V1  = OF_Y2 + kM2*5*kB;    // 192*16
constexpr int OF_V2  = OF_V1 + kM1*3*kB;    // 160*16
constexpr int OF_WENV= OF_V2 + kM2*5*kB;    // 224*16
constexpr int OF_COEF= OF_WENV + kT0*kB;    // 9*16 (k-major)
constexpr int OF_LG  = OF_COEF + 9*kB;      // 128
constexpr int OF_AID = OF_LG + 128;         // 16 ints
constexpr int OF_CEN = OF_AID + kB;         // 16 ints
constexpr int kSmemFloats = OF_CEN + kB;    // = 32304 floats = 129216 B

__device__ __forceinline__ void fma8(float* acc, const float* sm, int off, float w) {
  const float4 a = *(const float4*)(sm + off);
  const float4 b = *(const float4*)(sm + off + 4);
  acc[0] += a.x*w; acc[1] += a.y*w; acc[2] += a.z*w; acc[3] += a.w*w;
  acc[4] += b.x*w; acc[5] += b.y*w; acc[6] += b.z*w; acc[7] += b.w*w;
}

__global__ __launch_bounds__(kTPB)
void edge_kernel(const float* __restrict__ latents,
                 const float* __restrict__ nodef,
                 const float* __restrict__ edgef,
                 const float* __restrict__ mg,
                 const float* __restrict__ D1,
                 const float* __restrict__ D2,
                 const float* __restrict__ Wg,
                 const float* __restrict__ Wm,
                 const float* __restrict__ W0e,
                 const float* __restrict__ W0s,
                 const float* __restrict__ W1e,
                 const float* __restrict__ W1s,
                 const float* __restrict__ W2e,
                 const float* __restrict__ W2s,
                 const float* __restrict__ Wp0,
                 const float* __restrict__ bp0,
                 const float* __restrict__ Wp1,
                 const float* __restrict__ Wp2,
                 const float* __restrict__ Wenv,
                 const int* __restrict__ eidx,
                 const int* __restrict__ act,
                 float* __restrict__ accw)
{
  extern __shared__ float sm[];
  int* aid = (int*)(sm + OF_AID);
  int* cen = (int*)(sm + OF_CEN);
  const int t = threadIdx.x;
  const int base = blockIdx.x * kB;

  if (t < kB) {
    int a = act[base + t];
    aid[t] = a;
    cen[t] = eidx[a];   // row 0 of (2,E)
  }
  __syncthreads();

  // ---- stage latents (transposed) ----
  for (int i = t; i < kB*kLat; i += kTPB) {
    int b = i >> 7, l = i & (kLat - 1);
    sm[OF_LAT + l*kB + b] = latents[(size_t)aid[b]*kLat + l];
  }
  // ---- stage x0 = [n0 | e0] ----
  for (int i = t; i < kB*kC0; i += kTPB) {
    int b = i / kC0, c = i - b*kC0;
    float v = (c < kM0) ? nodef[(size_t)cen[b]*kNFD + c]
                        : edgef[(size_t)(base+b)*kEFD + (c - kM0)];
    sm[OF_X0 + c*kB + b] = v;
  }
  // ---- stage x1 rotated: x1r[c][m] = sum_n D1[m][n] x1[c][n] ----
  for (int i = t; i < kB*kC1*3; i += kTPB) {
    int b = i / (kC1*3), r = i - b*(kC1*3);
    int c = r / 3, m = r - c*3;
    const float* d = D1 + (size_t)(base+b)*9 + m*3;
    float a = 0.f;
    #pragma unroll
    for (int n = 0; n < 3; ++n) {
      float xv = (c < kM1) ? nodef[(size_t)cen[b]*kNFD + kM0 + c*3 + n]
                           : edgef[(size_t)(base+b)*kEFD + 64 + (c-kM1)*3 + n];
      a += d[n]*xv;
    }
    sm[OF_X1R + r*kB + b] = a;
  }
  // ---- stage x2 rotated ----
  for (int i = t; i < kB*kC2*5; i += kTPB) {
    int b = i / (kC2*5), r = i - b*(kC2*5);
    int c = r / 5, m = r - c*5;
    const float* d = D2 + (size_t)(base+b)*25 + m*5;
    float a = 0.f;
    #pragma unroll
    for (int n = 0; n < 5; ++n) {
      float xv = (c < kM2) ? nodef[(size_t)cen[b]*kNFD + 320 + c*5 + n]
                           : edgef[(size_t)(base+b)*kEFD + 160 + (c-kM2)*5 + n];
      a += d[n]*xv;
    }
    sm[OF_X2R + r*kB + b] = a;
  }
  __syncthreads();

  // ---- gate logits: lat@Wg + mg@Wm ----
  if (t < kB*8) {
    int b = t >> 3, e = t & 7;
    float lg = 0.f;
    for (int l = 0; l < kLat; ++l)
      lg += sm[OF_LAT + l*kB + b]*Wg[l*8 + e] + mg[l]*Wm[l*8 + e];
    sm[OF_LG + t] = lg;
  }
  __syncthreads();
  if (t < kB) {
    float mx = -1e30f;
    #pragma unroll
    for (int e = 0; e < 8; ++e) mx = fmaxf(mx, sm[OF_LG + t*8 + e]);
    float s = 0.f, ex[8];
    #pragma unroll
    for (int e = 0; e < 8; ++e) { ex[e] = __expf(sm[OF_LG + t*8 + e] - mx); s += ex[e]; }
    float inv = 1.f / s;
    #pragma unroll
    for (int e = 0; e < 8; ++e) sm[OF_COEF + e*kB + t] = ex[e]*inv;
    sm[OF_COEF + 8*kB + t] = 1.f;   // shared-weight coefficient
  }
  __syncthreads();

  // ---- wenv = lat @ Wenv / sqrt(128) ----
  if (t < 2*kT0) {
    int o = t % kT0, b0 = (t / kT0) * 8;
    float acc[8] = {};
    for (int l = 0; l < kLat; ++l)
      fma8(acc, sm, OF_LAT + l*kB + b0, Wenv[l*kT0 + o]);
    #pragma unroll
    for (int j = 0; j < 8; ++j)
      sm[OF_WENV + o*kB + b0 + j] = acc[j]*0.08838834764831845f;
  }

  // ---- t0 = mix0(x0): acc += coef_k * (x0 . W_k[:,o]) ----
  if (t < 2*kT0) {
    int o = t % kT0, b0 = (t / kT0) * 8;
    float acc[8] = {};
    for (int k = 0; k < 9; ++k) {
      const float* Wk = (k < 8) ? (W0e + (size_t)k*kC0*kT0) : W0s;
      float z[8] = {};
      for (int c = 0; c < kC0; ++c)
        fma8(z, sm, OF_X0 + c*kB + b0, Wk[c*kT0 + o]);
      #pragma unroll
      for (int j = 0; j < 8; ++j) acc[j] += sm[OF_COEF + k*kB + b0 + j]*z[j];
    }
    if (o < kM0) {
      #pragma unroll
      for (int j = 0; j < 8; ++j) {
        float v = acc[j]*0.07216878364870323f;          // 1/sqrt(192)
        sm[OF_S + o*kB + b0 + j] = v / (1.f + __expf(-v));  // silu
      }
    } else {
      #pragma unroll
      for (int j = 0; j < 8; ++j) {
        float v = acc[j]*0.07216878364870323f;
        sm[OF_T0G + (o-kM0)*kB + b0 + j] = 1.f/(1.f + __expf(-v)); // sigmoid
      }
    }
  }

  // ---- y1 = mix1(x1r) ----
  if (t < 2*192) {
    int q = t % 192, b0 = (t / 192) * 8;
    int m = q / 64, o = q - m*64;
    float acc[8] = {};
    for (int k = 0; k < 9; ++k) {
      const float* Wk = (k < 8) ? (W1e + (size_t)k*kC1*kM1) : W1s;
      float z[8] = {};
      for (int c = 0; c < kC1; ++c)
        fma8(z, sm, OF_X1R + (c*3+m)*kB + b0, Wk[c*kM1 + o]);
      #pragma unroll
      for (int j = 0; j < 8; ++j) acc[j] += sm[OF_COEF + k*kB + b0 + j]*z[j];
    }
    #pragma unroll
    for (int j = 0; j < 8; ++j)
      sm[OF_Y1 + (o*3+m)*kB + b0 + j] = acc[j]*0.10206207261596577f; // 1/sqrt(96)
  }

  // ---- y2 = mix2(x2r) ----
  if (t < 2*160) {
    int q = t % 160, b0 = (t / 160) * 8;
    int m = q / 32, o = q - m*32;
    float acc[8] = {};
    for (int k = 0; k < 9; ++k) {
      const float* Wk = (k < 8) ? (W2e + (size_t)k*kC2*kM2) : W2s;
      float z[8] = {};
      for (int c = 0; c < kC2; ++c)
        fma8(z, sm, OF_X2R + (c*5+m)*kB + b0, Wk[c*kM2 + o]);
      #pragma unroll
      for (int j = 0; j < 8; ++j) acc[j] += sm[OF_COEF + k*kB + b0 + j]*z[j];
    }
    #pragma unroll
    for (int j = 0; j < 8; ++j)
      sm[OF_Y2 + (o*5+m)*kB + b0 + j] = acc[j]*0.14433756729740643f; // 1/sqrt(48)
  }
  __syncthreads();

  // ---- rotate back (t1 = D1 @ y1, t2 = D2 @ y2) + sigmoid gating ----
  for (int i = t; i < kB*kM1*3; i += kTPB) {
    int b = i / 192, r = i - b*192, o = r/3, n = r - o*3;
    const float* d = D1 + (size_t)(base+b)*9 + n*3;
    float a = d[0]*sm[OF_Y1 + (o*3+0)*kB + b]
            + d[1]*sm[OF_Y1 + (o*3+1)*kB + b]
            + d[2]*sm[OF_Y1 + (o*3+2)*kB + b];
    sm[OF_V1 + (o*3+n)*kB + b] = a * sm[OF_T0G + o*kB + b];
  }
  for (int i = t; i < kB*kM2*5; i += kTPB) {
    int b = i / 160, r = i - b*160, o = r/5, n = r - o*5;
    const float* d = D2 + (size_t)(base+b)*25 + n*5;
    float a = 0.f;
    #pragma unroll
    for (int m = 0; m < 5; ++m) a += d[m]*sm[OF_Y2 + (o*5+m)*kB + b];
    sm[OF_V2 + (o*5+n)*kB + b] = a * sm[OF_T0G + (64+o)*kB + b];
  }
  __syncthreads();

  // ---- projections, env scaling, segment-sum atomics ----
  const float RN = 0.22360679774997896f;   // 1/sqrt(20)
  if (t < 256) {
    int o = t & 127, b0 = (t >> 7) * 8;
    float acc[8] = {};
    for (int c = 0; c < kM0; ++c)
      fma8(acc, sm, OF_S + c*kB + b0, Wp0[c*kM0 + o]);
    float bias = bp0[o];
    #pragma unroll
    for (int j = 0; j < 8; ++j) {
      float v = (acc[j]*0.08838834764831845f + bias) * sm[OF_WENV + o*kB + b0 + j] * RN;
      atomicAdd(&accw[(size_t)cen[b0+j]*kNFD + o], v);
    }
  }
  if (t < 384) {
    int q = t % 192, b0 = (t / 192) * 8;
    int m = q / 64, o = q - m*64;
    float acc[8] = {};
    for (int c = 0; c < kM1; ++c)
      fma8(acc, sm, OF_V1 + (c*3+m)*kB + b0, Wp1[c*kM1 + o]);
    #pragma unroll
    for (int j = 0; j < 8; ++j) {
      float v = acc[j]*0.125f * sm[OF_WENV + (kM0+o)*kB + b0 + j] * RN;
      atomicAdd(&accw[(size_t)cen[b0+j]*kNFD + kM0 + o*3 + m], v);
    }
  }
  if (t < 320) {
    int q = t % 160, b0 = (t / 160) * 8;
    int m = q / 32, o = q - m*32;
    float acc[8] = {};
    for (int c = 0; c < kM2; ++c)
      fma8(acc, sm, OF_V2 + (c*5+m)*kB + b0, Wp2[c*kM2 + o]);
    #pragma unroll
    for (int j = 0; j < 8; ++j) {
      float v = acc[j]*0.17677669529663687f * sm[OF_WENV + (192+o)*kB + b0 + j] * RN;
      atomicAdd(&accw[(size_t)cen[b0+j]*kNFD + 320 + o*5 + m], v);
    }
  }
}

__global__ __launch_bounds__(256)
void node_kernel(const float* __restrict__ nodef,
                 const float* __restrict__ onehot,
                 const float* __restrict__ Woh0,
                 const float* __restrict__ Woh1,
                 const float* __restrict__ Woh2,
                 const float* __restrict__ accw,
                 float* __restrict__ out)
{
  __shared__ int tn;
  const int n = blockIdx.x;
  const int t = threadIdx.x;
  if (t < kNT && onehot[(size_t)n*kNT + t] > 0.5f) tn = t;
  __syncthreads();
  const int ty = tn;
  const float c_old = 0.8944271909999159f;   // 1/sqrt(1.25)
  const float c_new = 0.4472135954999579f;   // 0.5/sqrt(1.25)
  const float invs  = 0.10259783520851541f;  // 1/sqrt(95)
  for (int j = t; j < kNFD; j += 256) {
    float h = c_old*nodef[(size_t)n*kNFD + j] + c_new*accw[(size_t)n*kNFD + j];
    float f;
    if (j < 128)      f = Woh0[j*kNT + ty];
    else if (j < 320) f = Woh1[((j-128)/3)*kNT + ty];
    else              f = Woh2[((j-320)/5)*kNT + ty];
    out[(size_t)n*kNFD + j] = h*(1.f + f*invs);
  }
}

} // namespace

extern "C" void kernel_launch(void* const* d_in, const int* in_sizes, int n_in,
                              void* d_out, int out_size, void* d_ws, size_t ws_size,
                              hipStream_t stream)
{
  (void)in_sizes; (void)n_in; (void)out_size; (void)ws_size;
  const float* latents = (const float*)d_in[0];
  const float* nodef   = (const float*)d_in[1];
  const float* edgef   = (const float*)d_in[2];
  // d_in[3] edge_vector: unused by reference
  const float* mg      = (const float*)d_in[4];
  const float* D1      = (const float*)d_in[5];
  const float* D2      = (const float*)d_in[6];
  const float* onehot  = (const float*)d_in[7];
  const float* Wg      = (const float*)d_in[8];
  const float* Wm      = (const float*)d_in[9];
  const float* W0e     = (const float*)d_in[10];
  const float* W0s     = (const float*)d_in[11];
  const float* W1e     = (const float*)d_in[12];
  const float* W1s     = (const float*)d_in[13];
  const float* W2e     = (const float*)d_in[14];
  const float* W2s     = (const float*)d_in[15];
  const float* Wp0     = (const float*)d_in[16];
  const float* bp0     = (const float*)d_in[17];
  const float* Wp1     = (const float*)d_in[18];
  const float* Wp2     = (const float*)d_in[19];
  const float* Wenv    = (const float*)d_in[20];
  const float* Woh0    = (const float*)d_in[21];
  const float* Woh1    = (const float*)d_in[22];
  const float* Woh2    = (const float*)d_in[23];
  // d_in[24] atom_type: unused by reference (node_onehot is the truth)
  const int* eidx      = (const int*)d_in[25];
  const int* act       = (const int*)d_in[26];
  float* accw = (float*)d_ws;            // N x 480 f32 accumulator
  float* out  = (float*)d_out;

  hipMemsetAsync(accw, 0, (size_t)kN*kNFD*sizeof(float), stream);

  hipFuncSetAttribute((const void*)edge_kernel,
                      hipFuncAttributeMaxDynamicSharedMemorySize,
                      kSmemFloats*(int)sizeof(float));

  edge_kernel<<<kE/kB, kTPB, kSmemFloats*sizeof(float), stream>>>(
      latents, nodef, edgef, mg, D1, D2, Wg, Wm,
      W0e, W0s, W1e, W1s, W2e, W2s,
      Wp0, bp0, Wp1, Wp2, Wenv, eidx, act, accw);

  node_kernel<<<kN, 256, 0, stream>>>(nodef, onehot, Woh0, Woh1, Woh2, accw, out);
}

// Round 2
// 2668.718 us; speedup vs baseline: 9.3210x; 9.3210x over previous
//
#include <hip/hip_runtime.h>
#include <math.h>

namespace {

typedef __attribute__((ext_vector_type(8))) short short8;
typedef __attribute__((ext_vector_type(4))) float f32x4;

constexpr int kN   = 10000;
constexpr int kE   = 200000;
constexpr int kNT  = 95;
constexpr int kNFD = 480;

__device__ __forceinline__ ushort bf(float f) {
  union { float f; uint u; } c; c.f = f;
  uint r = c.u + 0x7FFF + ((c.u >> 16) & 1);
  return (ushort)(r >> 16);
}
__device__ __forceinline__ float fb(ushort u) {
  union { uint u; float f; } c; c.u = ((uint)u) << 16;
  return c.f;
}

// ---------------------------------------------------------------------------
// Weight repack into MFMA B-fragment layout:
// dst[(((e*NT + nt)*NKp + kc)*64 + lane)*8 + i] = W_e[k][n], k=kc*32+(lane>>4)*8+i,
// n = nt*16 + (lane&15); zero beyond Kreal.
// ---------------------------------------------------------------------------
__device__ __forceinline__ void packone(int u, const float* We, const float* Ws,
                                        int expStride, int Kreal, int N, int NT,
                                        int NKp, ushort* d) {
  int i = u & 7;
  int lane = (u >> 3) & 63;
  int rest = u >> 9;
  int kc = rest % NKp; rest /= NKp;
  int nt = rest % NT;
  int e  = rest / NT;
  int k = kc*32 + (lane >> 4)*8 + i;
  int n = nt*16 + (lane & 15);
  float v = 0.f;
  if (k < Kreal) {
    const float* s = (Ws != nullptr && e == 8) ? Ws : (We + (size_t)e*expStride);
    v = s[(size_t)k*N + n];
  }
  d[u] = bf(v);
}

constexpr int PK0   = 0;        // mix0: 9*14*6*512
constexpr int PK1   = 387072;   // mix1: 9*4*3*512
constexpr int PK2   = 442368;   // mix2: 9*2*2*512
constexpr int PKENV = 460800;   // wenv: 14*4*512
constexpr int PKP0  = 489472;   // p0:   8*4*512
constexpr int PKP1  = 505856;   // p1:   4*2*512
constexpr int PKP2  = 509952;   // p2:   2*1*512
constexpr int PKTOT = 510976;

__global__ __launch_bounds__(256)
void pack_k(const float* __restrict__ W0e, const float* __restrict__ W0s,
            const float* __restrict__ W1e, const float* __restrict__ W1s,
            const float* __restrict__ W2e, const float* __restrict__ W2s,
            const float* __restrict__ Wenv, const float* __restrict__ Wp0,
            const float* __restrict__ Wp1, const float* __restrict__ Wp2,
            ushort* __restrict__ dst) {
  int gid = blockIdx.x*256 + threadIdx.x;
  if (gid >= PKTOT) return;
  if (gid < PK1)        packone(gid - PK0,   W0e, W0s, 192*224, 192, 224, 14, 6, dst + PK0);
  else if (gid < PK2)   packone(gid - PK1,   W1e, W1s, 96*64,    96,  64,  4, 3, dst + PK1);
  else if (gid < PKENV) packone(gid - PK2,   W2e, W2s, 48*32,    48,  32,  2, 2, dst + PK2);
  else if (gid < PKP0)  packone(gid - PKENV, Wenv, nullptr, 0,  128, 224, 14, 4, dst + PKENV);
  else if (gid < PKP1)  packone(gid - PKP0,  Wp0, nullptr, 0,   128, 128,  8, 4, dst + PKP0);
  else if (gid < PKP2)  packone(gid - PKP1,  Wp1, nullptr, 0,    64,  64,  4, 2, dst + PKP1);
  else                  packone(gid - PKP2,  Wp2, nullptr, 0,    32,  32,  2, 1, dst + PKP2);
}

// ---------------------------------------------------------------------------
// Prep: per-edge gates (softmax coef, +1.0 shared), cen, bf16 x0, rotated bf16
// x1r (rows a*3+m, 96 cols), x2r (rows a*5+m, 64 cols zero-padded 48..63).
// ---------------------------------------------------------------------------
__global__ __launch_bounds__(256)
void prep_k(const float* __restrict__ latents, const float* __restrict__ nodef,
            const float* __restrict__ edgef, const float* __restrict__ mgv,
            const float* __restrict__ D1, const float* __restrict__ D2,
            const float* __restrict__ Wg, const float* __restrict__ Wm,
            const int* __restrict__ eidx, const int* __restrict__ act,
            float* __restrict__ coefg, int* __restrict__ ceng,
            ushort* __restrict__ x0, ushort* __restrict__ x1r,
            ushort* __restrict__ x2r) {
  __shared__ float latl[64*129];
  __shared__ float lgl[64*8];
  __shared__ int aidl[64], cenl[64];
  const int tid = threadIdx.x;
  const int base = blockIdx.x*64;

  if (tid < 64) {
    int a = act[base + tid];
    aidl[tid] = a;
    int c = eidx[a];
    cenl[tid] = c;
    ceng[base + tid] = c;
  }
  __syncthreads();

  for (int u = tid; u < 64*128; u += 256) {
    int e = u >> 7, l = u & 127;
    latl[e*129 + l] = latents[(size_t)aidl[e]*128 + l];
  }
  __syncthreads();

  for (int u = tid; u < 64*8; u += 256) {
    int e = u >> 3, x = u & 7;
    float s = 0.f;
    for (int l = 0; l < 128; ++l)
      s += latl[e*129 + l]*Wg[l*8 + x] + mgv[l]*Wm[l*8 + x];
    lgl[u] = s;
  }
  __syncthreads();

  if (tid < 64) {
    float mx = -1e30f;
    #pragma unroll
    for (int x = 0; x < 8; ++x) mx = fmaxf(mx, lgl[tid*8 + x]);
    float ssum = 0.f, ex[8];
    #pragma unroll
    for (int x = 0; x < 8; ++x) { ex[x] = __expf(lgl[tid*8 + x] - mx); ssum += ex[x]; }
    float inv = 1.f/ssum;
    #pragma unroll
    for (int x = 0; x < 8; ++x) coefg[(size_t)(base + tid)*9 + x] = ex[x]*inv;
    coefg[(size_t)(base + tid)*9 + 8] = 1.f;
  }

  // x0 = [n0(128) | e0(64)]
  for (int u = tid; u < 64*192; u += 256) {
    int e = u/192, c = u - e*192;
    size_t a = base + e;
    float v = (c < 128) ? nodef[(size_t)cenl[e]*kNFD + c]
                        : edgef[a*240 + (c - 128)];
    x0[a*192 + c] = bf(v);
  }
  // x1r[a*3+m][c] = sum_n D1[a][m][n]*x1[c][n];  x1: c<64 node(128+c*3+n) else edge(64+(c-64)*3+n)
  for (int u = tid; u < 3*64*96; u += 256) {
    int mm = u/(64*96), r = u - mm*64*96;
    int e = r/96, c = r - e*96;
    size_t a = base + e;
    const float* dd = D1 + a*9 + mm*3;
    float s = 0.f;
    #pragma unroll
    for (int n = 0; n < 3; ++n) {
      float xv = (c < 64) ? nodef[(size_t)cenl[e]*kNFD + 128 + c*3 + n]
                          : edgef[a*240 + 64 + (c - 64)*3 + n];
      s += dd[n]*xv;
    }
    x1r[(a*3 + mm)*96 + c] = bf(s);
  }
  // x2r[a*5+m][c], 64 cols (48 real + 16 zero pad)
  for (int u = tid; u < 5*64*64; u += 256) {
    int mm = u/(64*64), r = u - mm*64*64;
    int e = r/64, c = r - e*64;
    size_t a = base + e;
    ushort o = 0;
    if (c < 48) {
      const float* dd = D2 + a*25 + mm*5;
      float s = 0.f;
      #pragma unroll
      for (int n = 0; n < 5; ++n) {
        float xv = (c < 32) ? nodef[(size_t)cenl[e]*kNFD + 320 + c*5 + n]
                            : edgef[a*240 + 160 + (c - 32)*5 + n];
        s += dd[n]*xv;
      }
      o = bf(s);
    }
    x2r[(a*5 + mm)*64 + c] = o;
  }
}

// ---------------------------------------------------------------------------
// Templated MFMA GEMM. BM=128 rows/block, 8 waves = 4 rowgroups x 2 colgroups.
// Full-K A tile staged once to LDS, A-fragments cached in registers,
// per-expert z accumulators folded via gate coef.
// EPI 0: plain bf16 store.  EPI 1: silu(<128)/sigmoid(>=128) bf16 store (N=224).
// EPI 2: (acc*norm [+bias]) * wenv * 1/sqrt(20) -> atomicAdd into accw.
// ---------------------------------------------------------------------------
template<int DIV, int K1, int NK, int N, int NEXP, int EPI, bool AF32>
__global__ __launch_bounds__(512)
void gemm_k(const ushort* __restrict__ A, const float* __restrict__ Af,
            const int* __restrict__ ridx, int strideA,
            const ushort* __restrict__ Bpk, const float* __restrict__ coefg,
            int rowsReal, float norm,
            ushort* __restrict__ outbf, const float* __restrict__ bias,
            const ushort* __restrict__ wenvbf, const int* __restrict__ cen,
            float* __restrict__ accw, int WCOL, int OB) {
  constexpr int NT  = N/16;
  constexpr int CTW = NT/2;
  constexpr int LDA = K1 + 8;               // bf16 units; (K1+8)%8==0 -> 16B rows
  __shared__ ushort Asm[128*LDA];
  __shared__ float coefsm[(NEXP > 1) ? 128*NEXP : 1];

  const int tid = threadIdx.x;
  const int row0 = blockIdx.x*128;

  constexpr int C8 = K1/8;
  for (int u = tid; u < 128*C8; u += 512) {
    int r = u / C8, c8 = u - r*C8;
    int gr = row0 + r;
    uint4 v = {0u,0u,0u,0u};
    if (gr < rowsReal) {
      if constexpr (AF32) {
        const float* s = Af + (size_t)(ridx ? ridx[gr] : gr)*strideA + c8*8;
        float4 f0 = *(const float4*)s;
        float4 f1 = *(const float4*)(s + 4);
        v.x = (uint)bf(f0.x) | ((uint)bf(f0.y) << 16);
        v.y = (uint)bf(f0.z) | ((uint)bf(f0.w) << 16);
        v.z = (uint)bf(f1.x) | ((uint)bf(f1.y) << 16);
        v.w = (uint)bf(f1.z) | ((uint)bf(f1.w) << 16);
      } else {
        v = *(const uint4*)(A + (size_t)gr*strideA + c8*8);
      }
    }
    *(uint4*)(&Asm[r*LDA + c8*8]) = v;
  }
  if constexpr (NEXP > 1) {
    for (int u = tid; u < 128*NEXP; u += 512) {
      int r = u / NEXP, e = u - r*NEXP;
      int a = (row0 + r)/DIV;
      coefsm[r*NEXP + e] = coefg[(size_t)a*NEXP + e];
    }
  }
  __syncthreads();

  const int lane = tid & 63, wid = tid >> 6;
  const int rg = wid & 3, cg = wid >> 2;
  const int rbase = rg*32;
  const int lrow = lane & 15, lkb = lane >> 4;

  short8 af[2][NK];
  #pragma unroll
  for (int rt = 0; rt < 2; ++rt)
    #pragma unroll
    for (int kc = 0; kc < NK; ++kc)
      af[rt][kc] = *(const short8*)(&Asm[(rbase + rt*16 + lrow)*LDA + kc*32 + lkb*8]);

  f32x4 acc[2][CTW];
  #pragma unroll
  for (int rt = 0; rt < 2; ++rt)
    #pragma unroll
    for (int ct = 0; ct < CTW; ++ct)
      acc[rt][ct] = f32x4{0.f,0.f,0.f,0.f};

  union BU { uint4 u; short8 s; };

  if constexpr (NEXP == 1) {
    #pragma unroll
    for (int ct = 0; ct < CTW; ++ct) {
      const ushort* bp = Bpk + ((size_t)(cg*CTW + ct)*NK*64 + lane)*8;
      #pragma unroll
      for (int kc = 0; kc < NK; ++kc) {
        BU b; b.u = *(const uint4*)(bp + (size_t)kc*512);
        acc[0][ct] = __builtin_amdgcn_mfma_f32_16x16x32_bf16(af[0][kc], b.s, acc[0][ct], 0, 0, 0);
        acc[1][ct] = __builtin_amdgcn_mfma_f32_16x16x32_bf16(af[1][kc], b.s, acc[1][ct], 0, 0, 0);
      }
    }
  } else {
    for (int e = 0; e < NEXP; ++e) {
      float cf[2][4];
      #pragma unroll
      for (int rt = 0; rt < 2; ++rt)
        #pragma unroll
        for (int q = 0; q < 4; ++q)
          cf[rt][q] = coefsm[(rbase + rt*16 + lkb*4 + q)*NEXP + e];
      #pragma unroll
      for (int ct = 0; ct < CTW; ++ct) {
        const ushort* bp = Bpk + ((size_t)((e*NT + cg*CTW + ct)*NK)*64 + lane)*8;
        f32x4 z0 = {0.f,0.f,0.f,0.f}, z1 = {0.f,0.f,0.f,0.f};
        #pragma unroll
        for (int kc = 0; kc < NK; ++kc) {
          BU b; b.u = *(const uint4*)(bp + (size_t)kc*512);
          z0 = __builtin_amdgcn_mfma_f32_16x16x32_bf16(af[0][kc], b.s, z0, 0, 0, 0);
          z1 = __builtin_amdgcn_mfma_f32_16x16x32_bf16(af[1][kc], b.s, z1, 0, 0, 0);
        }
        #pragma unroll
        for (int q = 0; q < 4; ++q) {
          acc[0][ct][q] += cf[0][q]*z0[q];
          acc[1][ct][q] += cf[1][q]*z1[q];
        }
      }
    }
  }

  // epilogue
  #pragma unroll
  for (int rt = 0; rt < 2; ++rt) {
    #pragma unroll
    for (int ct = 0; ct < CTW; ++ct) {
      #pragma unroll
      for (int q = 0; q < 4; ++q) {
        int gr = row0 + rbase + rt*16 + lkb*4 + q;
        if (gr >= rowsReal) continue;
        int o = (cg*CTW + ct)*16 + lrow;
        float val = acc[rt][ct][q]*norm;
        if constexpr (EPI == 0) {
          outbf[(size_t)gr*N + o] = bf(val);
        } else if constexpr (EPI == 1) {
          float av = (o < 128) ? (val/(1.f + __expf(-val)))
                               : (1.f/(1.f + __expf(-val)));
          outbf[(size_t)gr*N + o] = bf(av);
        } else {
          int a = gr/DIV, n = gr - a*DIV;
          if (bias != nullptr) val += bias[o];
          float w = fb(wenvbf[(size_t)a*224 + WCOL + o]);
          val *= w*0.22360679774997896f;   // 1/sqrt(AVG_NEIGH)
          atomicAdd(accw + (size_t)cen[a]*kNFD + OB + o*DIV + n, val);
        }
      }
    }
  }
}

// ---------------------------------------------------------------------------
// Rotate-back + sigmoid gating: v1[a*3+n][c] = g1[c]*sum_m D1[n][m]*y1[a*3+m][c]
// ---------------------------------------------------------------------------
__global__ __launch_bounds__(256)
void mid_k(const ushort* __restrict__ y1, const ushort* __restrict__ y2,
           const ushort* __restrict__ t0act, const float* __restrict__ D1,
           const float* __restrict__ D2, ushort* __restrict__ v1,
           ushort* __restrict__ v2) {
  const int base = blockIdx.x*64;
  for (int u = threadIdx.x; u < 64*192; u += 256) {
    int e = u/192, r = u - e*192;
    int n = r >> 6, c = r & 63;
    size_t a = base + e;
    float s = 0.f;
    #pragma unroll
    for (int m = 0; m < 3; ++m)
      s += D1[a*9 + n*3 + m]*fb(y1[(a*3 + m)*64 + c]);
    s *= fb(t0act[a*224 + 128 + c]);
    v1[(a*3 + n)*64 + c] = bf(s);
  }
  for (int u = threadIdx.x; u < 64*160; u += 256) {
    int e = u/160, r = u - e*160;
    int n = r >> 5, c = r & 31;
    size_t a = base + e;
    float s = 0.f;
    #pragma unroll
    for (int m = 0; m < 5; ++m)
      s += D2[a*25 + n*5 + m]*fb(y2[(a*5 + m)*32 + c]);
    s *= fb(t0act[a*224 + 192 + c]);
    v2[(a*5 + n)*32 + c] = bf(s);
  }
}

// ---------------------------------------------------------------------------
// Node finalize: residual + one-hot modulation.
// ---------------------------------------------------------------------------
__global__ __launch_bounds__(256)
void node_k(const float* __restrict__ nodef, const float* __restrict__ onehot,
            const float* __restrict__ Woh0, const float* __restrict__ Woh1,
            const float* __restrict__ Woh2, const float* __restrict__ accw,
            float* __restrict__ out) {
  __shared__ int tn;
  const int n = blockIdx.x;
  const int t = threadIdx.x;
  if (t < kNT && onehot[(size_t)n*kNT + t] > 0.5f) tn = t;
  __syncthreads();
  const int ty = tn;
  const float c_old = 0.8944271909999159f;
  const float c_new = 0.4472135954999579f;
  const float invs  = 0.10259783520851541f;
  for (int j = t; j < kNFD; j += 256) {
    float h = c_old*nodef[(size_t)n*kNFD + j] + c_new*accw[(size_t)n*kNFD + j];
    float f;
    if (j < 128)      f = Woh0[j*kNT + ty];
    else if (j < 320) f = Woh1[((j - 128)/3)*kNT + ty];
    else              f = Woh2[((j - 320)/5)*kNT + ty];
    out[(size_t)n*kNFD + j] = h*(1.f + f*invs);
  }
}

// workspace layout (bytes)
constexpr size_t OFF_ACCW = 0;            // 10000*480*4      = 19,200,000
constexpr size_t OFF_COEF = 19200000;     // 200064*9*4       =  7,202,304
constexpr size_t OFF_CEN  = 26402304;     // 200064*4         =    800,256
constexpr size_t OFF_X0   = 27202560;     // 200064*192*2     = 76,824,576  (later v1)
constexpr size_t OFF_X1R  = 104027136;    // 600192*96*2      = 115,236,864 (later v2)
constexpr size_t OFF_X2R  = 219264000;    // 1000064*64*2     = 128,008,192
constexpr size_t OFF_WENV = 347272192;    // 200064*224*2     = 89,628,672
constexpr size_t OFF_T0A  = 436900864;    // 200064*224*2     = 89,628,672
constexpr size_t OFF_Y1   = 526529536;    // 600192*64*2      = 76,824,576
constexpr size_t OFF_Y2   = 603354112;    // 1000064*32*2     = 64,004,096
constexpr size_t OFF_PACK = 667358208;    // 510976*2         =  1,021,952
// total ~668.4 MB

} // namespace

extern "C" void kernel_launch(void* const* d_in, const int* in_sizes, int n_in,
                              void* d_out, int out_size, void* d_ws, size_t ws_size,
                              hipStream_t stream) {
  (void)in_sizes; (void)n_in; (void)out_size; (void)ws_size;
  const float* latents = (const float*)d_in[0];
  const float* nodef   = (const float*)d_in[1];
  const float* edgef   = (const float*)d_in[2];
  const float* mg      = (const float*)d_in[4];
  const float* D1      = (const float*)d_in[5];
  const float* D2      = (const float*)d_in[6];
  const float* onehot  = (const float*)d_in[7];
  const float* Wg      = (const float*)d_in[8];
  const float* Wm      = (const float*)d_in[9];
  const float* W0e     = (const float*)d_in[10];
  const float* W0s     = (const float*)d_in[11];
  const float* W1e     = (const float*)d_in[12];
  const float* W1s     = (const float*)d_in[13];
  const float* W2e     = (const float*)d_in[14];
  const float* W2s     = (const float*)d_in[15];
  const float* Wp0     = (const float*)d_in[16];
  const float* bp0     = (const float*)d_in[17];
  const float* Wp1     = (const float*)d_in[18];
  const float* Wp2     = (const float*)d_in[19];
  const float* Wenv    = (const float*)d_in[20];
  const float* Woh0    = (const float*)d_in[21];
  const float* Woh1    = (const float*)d_in[22];
  const float* Woh2    = (const float*)d_in[23];
  const int* eidx      = (const int*)d_in[25];
  const int* act       = (const int*)d_in[26];

  char* ws = (char*)d_ws;
  float*  accw  = (float*)(ws + OFF_ACCW);
  float*  coef  = (float*)(ws + OFF_COEF);
  int*    ceng  = (int*)(ws + OFF_CEN);
  ushort* x0    = (ushort*)(ws + OFF_X0);
  ushort* x1r   = (ushort*)(ws + OFF_X1R);
  ushort* x2r   = (ushort*)(ws + OFF_X2R);
  ushort* wenv  = (ushort*)(ws + OFF_WENV);
  ushort* t0act = (ushort*)(ws + OFF_T0A);
  ushort* y1    = (ushort*)(ws + OFF_Y1);
  ushort* y2    = (ushort*)(ws + OFF_Y2);
  ushort* v1    = (ushort*)(ws + OFF_X0);    // alias: x0 dead after G_t0
  ushort* v2    = (ushort*)(ws + OFF_X1R);   // alias: x1r dead after G_y1
  ushort* pk    = (ushort*)(ws + OFF_PACK);
  float*  out   = (float*)d_out;

  hipMemsetAsync(accw, 0, (size_t)kN*kNFD*sizeof(float), stream);

  pack_k<<<(PKTOT + 255)/256, 256, 0, stream>>>(W0e, W0s, W1e, W1s, W2e, W2s,
                                                Wenv, Wp0, Wp1, Wp2, pk);

  prep_k<<<kE/64, 256, 0, stream>>>(latents, nodef, edgef, mg, D1, D2, Wg, Wm,
                                    eidx, act, coef, ceng, x0, x1r, x2r);

  // t0 = mix0(x0) -> silu/sigmoid activations
  gemm_k<1,192,6,224,9,1,false><<<1563, 512, 0, stream>>>(
      x0, nullptr, nullptr, 192, pk + PK0, coef, kE, 0.07216878364870323f,
      t0act, nullptr, nullptr, nullptr, nullptr, 0, 0);
  // wenv = latents[act] @ Wenv / sqrt(128)
  gemm_k<1,128,4,224,1,0,true><<<1563, 512, 0, stream>>>(
      nullptr, latents, act, 128, pk + PKENV, nullptr, kE, 0.08838834764831845f,
      wenv, nullptr, nullptr, nullptr, nullptr, 0, 0);
  // y1 = mix1(x1r)
  gemm_k<3,96,3,64,9,0,false><<<4688, 512, 0, stream>>>(
      x1r, nullptr, nullptr, 96, pk + PK1, coef, 3*kE, 0.10206207261596577f,
      y1, nullptr, nullptr, nullptr, nullptr, 0, 0);
  // y2 = mix2(x2r)
  gemm_k<5,64,2,32,9,0,false><<<7813, 512, 0, stream>>>(
      x2r, nullptr, nullptr, 64, pk + PK2, coef, 5*kE, 0.14433756729740643f,
      y2, nullptr, nullptr, nullptr, nullptr, 0, 0);

  mid_k<<<kE/64, 256, 0, stream>>>(y1, y2, t0act, D1, D2, v1, v2);

  // P0: silu-part of t0act (stride 224, first 128 cols) @ Wp0 -> atomic
  gemm_k<1,128,4,128,1,2,false><<<1563, 512, 0, stream>>>(
      t0act, nullptr, nullptr, 224, pk + PKP0, nullptr, kE, 0.08838834764831845f,
      nullptr, bp0, wenv, ceng, accw, 0, 0);
  // P1: v1 @ Wp1 -> atomic
  gemm_k<3,64,2,64,1,2,false><<<4688, 512, 0, stream>>>(
      v1, nullptr, nullptr, 64, pk + PKP1, nullptr, 3*kE, 0.125f,
      nullptr, nullptr, wenv, ceng, accw, 128, 128);
  // P2: v2 @ Wp2 -> atomic
  gemm_k<5,32,1,32,1,2,false><<<7813, 512, 0, stream>>>(
      v2, nullptr, nullptr, 32, pk + PKP2, nullptr, 5*kE, 0.17677669529663687f,
      nullptr, nullptr, wenv, ceng, accw, 192, 320);

  node_k<<<kN, 256, 0, stream>>>(nodef, onehot, Woh0, Woh1, Woh2, accw, out);
}

// Round 3
// 2485.026 us; speedup vs baseline: 10.0100x; 1.0739x over previous
//
#include <hip/hip_runtime.h>
#include <math.h>

namespace {

typedef __attribute__((ext_vector_type(8))) short short8;
typedef __attribute__((ext_vector_type(4))) float f32x4;

constexpr int kN   = 10000;
constexpr int kE   = 200000;
constexpr int kNT  = 95;
constexpr int kNFD = 480;

__device__ __forceinline__ ushort bf(float f) {
  union { float f; uint u; } c; c.f = f;
  uint r = c.u + 0x7FFF + ((c.u >> 16) & 1);
  return (ushort)(r >> 16);
}
__device__ __forceinline__ float fb(ushort u) {
  union { uint u; float f; } c; c.u = ((uint)u) << 16;
  return c.f;
}
__device__ __forceinline__ uint pk2(float a, float b) {
  return (uint)bf(a) | ((uint)bf(b) << 16);
}

// ---------------------------------------------------------------------------
// Weight repack into MFMA B-fragment layout (unchanged from R1).
// ---------------------------------------------------------------------------
__device__ __forceinline__ void packone(int u, const float* We, const float* Ws,
                                        int expStride, int Kreal, int N, int NT,
                                        int NKp, ushort* d) {
  int i = u & 7;
  int lane = (u >> 3) & 63;
  int rest = u >> 9;
  int kc = rest % NKp; rest /= NKp;
  int nt = rest % NT;
  int e  = rest / NT;
  int k = kc*32 + (lane >> 4)*8 + i;
  int n = nt*16 + (lane & 15);
  float v = 0.f;
  if (k < Kreal) {
    const float* s = (Ws != nullptr && e == 8) ? Ws : (We + (size_t)e*expStride);
    v = s[(size_t)k*N + n];
  }
  d[u] = bf(v);
}

constexpr int PK0   = 0;
constexpr int PK1   = 387072;
constexpr int PK2   = 442368;
constexpr int PKENV = 460800;
constexpr int PKP0  = 489472;
constexpr int PKP1  = 505856;
constexpr int PKP2  = 509952;
constexpr int PKTOT = 510976;

__global__ __launch_bounds__(256)
void pack_k(const float* __restrict__ W0e, const float* __restrict__ W0s,
            const float* __restrict__ W1e, const float* __restrict__ W1s,
            const float* __restrict__ W2e, const float* __restrict__ W2s,
            const float* __restrict__ Wenv, const float* __restrict__ Wp0,
            const float* __restrict__ Wp1, const float* __restrict__ Wp2,
            ushort* __restrict__ dst) {
  int gid = blockIdx.x*256 + threadIdx.x;
  if (gid >= PKTOT) return;
  if (gid < PK1)        packone(gid - PK0,   W0e, W0s, 192*224, 192, 224, 14, 6, dst + PK0);
  else if (gid < PK2)   packone(gid - PK1,   W1e, W1s, 96*64,    96,  64,  4, 3, dst + PK1);
  else if (gid < PKENV) packone(gid - PK2,   W2e, W2s, 48*32,    48,  32,  2, 2, dst + PK2);
  else if (gid < PKP0)  packone(gid - PKENV, Wenv, nullptr, 0,  128, 224, 14, 4, dst + PKENV);
  else if (gid < PKP1)  packone(gid - PKP0,  Wp0, nullptr, 0,   128, 128,  8, 4, dst + PKP0);
  else if (gid < PKP2)  packone(gid - PKP1,  Wp1, nullptr, 0,    64,  64,  4, 2, dst + PKP1);
  else                  packone(gid - PKP2,  Wp2, nullptr, 0,    32,  32,  2, 1, dst + PKP2);
}

// ---------------------------------------------------------------------------
// Prep (rewritten): 32 edges/block, 512 threads. LDS-stage nodef[cen]/edgef/
// latents rows via coalesced float4 loads; all compute reads LDS; all outputs
// stored as packed uint4 (8 bf16).
// ---------------------------------------------------------------------------
constexpr int PEB = 32;
constexpr int LDN = 488;   // nodef  LDS row stride (f32), 488%32=8
constexpr int LDE = 248;   // edgef  stride, 248%32=24
constexpr int LDL = 132;   // latent stride, 132%32=4
constexpr int PSM_FLOATS = PEB*(LDN + LDE + LDL) + PEB*8 + 2*PEB; // 28096
// bytes = 112384

__global__ __launch_bounds__(512)
void prep_k(const float* __restrict__ latents, const float* __restrict__ nodef,
            const float* __restrict__ edgef, const float* __restrict__ mgv,
            const float* __restrict__ D1, const float* __restrict__ D2,
            const float* __restrict__ Wg, const float* __restrict__ Wm,
            const int* __restrict__ eidx, const int* __restrict__ act,
            float* __restrict__ coefg, int* __restrict__ ceng,
            ushort* __restrict__ x0, ushort* __restrict__ x1r,
            ushort* __restrict__ x2r) {
  extern __shared__ float ps[];
  float* ndl = ps;                         // [32][488]
  float* edl = ps + PEB*LDN;               // [32][248]
  float* ltl = ps + PEB*(LDN + LDE);       // [32][132]
  float* lgl = ps + PEB*(LDN + LDE + LDL); // [32*8]
  int*   aidl = (int*)(lgl + PEB*8);       // [32]
  int*   cenl = aidl + PEB;                // [32]

  const int tid = threadIdx.x;
  const int base = blockIdx.x*PEB;

  if (tid < PEB) {
    int a = act[base + tid];
    aidl[tid] = a;
    int c = eidx[a];
    cenl[tid] = c;
    ceng[base + tid] = c;
  }
  __syncthreads();

  // stage nodef rows (120 float4 each)
  for (int u = tid; u < PEB*120; u += 512) {
    int e = u/120, q = u - e*120;
    float4 v = *(const float4*)(nodef + (size_t)cenl[e]*kNFD + q*4);
    *(float4*)(ndl + e*LDN + q*4) = v;
  }
  // stage edgef rows (60 float4)
  for (int u = tid; u < PEB*60; u += 512) {
    int e = u/60, q = u - e*60;
    float4 v = *(const float4*)(edgef + (size_t)(base + e)*240 + q*4);
    *(float4*)(edl + e*LDE + q*4) = v;
  }
  // stage latent rows (32 float4)
  for (int u = tid; u < PEB*32; u += 512) {
    int e = u >> 5, q = u & 31;
    float4 v = *(const float4*)(latents + (size_t)aidl[e]*128 + q*4);
    *(float4*)(ltl + e*LDL + q*4) = v;
  }
  __syncthreads();

  // gate logits
  if (tid < PEB*8) {
    int e = tid >> 3, x = tid & 7;
    float s = 0.f;
    for (int l = 0; l < 128; ++l)
      s += ltl[e*LDL + l]*Wg[l*8 + x] + mgv[l]*Wm[l*8 + x];
    lgl[tid] = s;
  }
  __syncthreads();

  if (tid < PEB) {
    float mx = -1e30f;
    #pragma unroll
    for (int x = 0; x < 8; ++x) mx = fmaxf(mx, lgl[tid*8 + x]);
    float ssum = 0.f, ex[8];
    #pragma unroll
    for (int x = 0; x < 8; ++x) { ex[x] = __expf(lgl[tid*8 + x] - mx); ssum += ex[x]; }
    float inv = 1.f/ssum;
    #pragma unroll
    for (int x = 0; x < 8; ++x) coefg[(size_t)(base + tid)*9 + x] = ex[x]*inv;
    coefg[(size_t)(base + tid)*9 + 8] = 1.f;
  }

  // x0 = [n0(128) | e0(64)], packed stores, 24 groups of 8 cols per edge
  for (int u = tid; u < PEB*24; u += 512) {
    int e = u/24, g = u - e*24;
    int c0 = g*8;
    const float* s = (g < 16) ? (ndl + e*LDN + c0) : (edl + e*LDE + (c0 - 128));
    uint4 o;
    o.x = pk2(s[0], s[1]); o.y = pk2(s[2], s[3]);
    o.z = pk2(s[4], s[5]); o.w = pk2(s[6], s[7]);
    *(uint4*)(x0 + (size_t)(base + e)*192 + c0) = o;
  }

  // x1r: rows (a*3+mm), 96 cols, 12 groups of 8
  for (int u = tid; u < PEB*3*12; u += 512) {
    int e = u/36, r = u - e*36;
    int mm = r/12, g = r - mm*12;
    int c0 = g*8;
    size_t a = base + e;
    const float* dd = D1 + a*9 + mm*3;
    float d0 = dd[0], d1 = dd[1], d2 = dd[2];
    float ov[8];
    if (g < 8) {
      const float* s = ndl + e*LDN + 128 + c0*3;
      #pragma unroll
      for (int j = 0; j < 8; ++j)
        ov[j] = d0*s[j*3] + d1*s[j*3 + 1] + d2*s[j*3 + 2];
    } else {
      const float* s = edl + e*LDE + 64 + (c0 - 64)*3;
      #pragma unroll
      for (int j = 0; j < 8; ++j)
        ov[j] = d0*s[j*3] + d1*s[j*3 + 1] + d2*s[j*3 + 2];
    }
    uint4 o;
    o.x = pk2(ov[0], ov[1]); o.y = pk2(ov[2], ov[3]);
    o.z = pk2(ov[4], ov[5]); o.w = pk2(ov[6], ov[7]);
    *(uint4*)(x1r + ((size_t)a*3 + mm)*96 + c0) = o;
  }

  // x2r: rows (a*5+mm), 64 cols (48 real + 16 zero), 8 groups of 8
  for (int u = tid; u < PEB*5*8; u += 512) {
    int e = u/40, r = u - e*40;
    int mm = r >> 3, g = r & 7;
    int c0 = g*8;
    size_t a = base + e;
    uint4 o = {0u,0u,0u,0u};
    if (g < 6) {
      const float* dd = D2 + a*25 + mm*5;
      float d0 = dd[0], d1 = dd[1], d2 = dd[2], d3 = dd[3], d4 = dd[4];
      const float* s = (g < 4) ? (ndl + e*LDN + 320 + c0*5)
                               : (edl + e*LDE + 160 + (c0 - 32)*5);
      float ov[8];
      #pragma unroll
      for (int j = 0; j < 8; ++j)
        ov[j] = d0*s[j*5] + d1*s[j*5+1] + d2*s[j*5+2] + d3*s[j*5+3] + d4*s[j*5+4];
      o.x = pk2(ov[0], ov[1]); o.y = pk2(ov[2], ov[3]);
      o.z = pk2(ov[4], ov[5]); o.w = pk2(ov[6], ov[7]);
    }
    *(uint4*)(x2r + ((size_t)a*5 + mm)*64 + c0) = o;
  }
}

// ---------------------------------------------------------------------------
// Templated MFMA GEMM (unchanged from R1).
// ---------------------------------------------------------------------------
template<int DIV, int K1, int NK, int N, int NEXP, int EPI, bool AF32>
__global__ __launch_bounds__(512)
void gemm_k(const ushort* __restrict__ A, const float* __restrict__ Af,
            const int* __restrict__ ridx, int strideA,
            const ushort* __restrict__ Bpk, const float* __restrict__ coefg,
            int rowsReal, float norm,
            ushort* __restrict__ outbf, const float* __restrict__ bias,
            const ushort* __restrict__ wenvbf, const int* __restrict__ cen,
            float* __restrict__ accw, int WCOL, int OB) {
  constexpr int NT  = N/16;
  constexpr int CTW = NT/2;
  constexpr int LDA = K1 + 8;
  __shared__ ushort Asm[128*LDA];
  __shared__ float coefsm[(NEXP > 1) ? 128*NEXP : 1];

  const int tid = threadIdx.x;
  const int row0 = blockIdx.x*128;

  constexpr int C8 = K1/8;
  for (int u = tid; u < 128*C8; u += 512) {
    int r = u / C8, c8 = u - r*C8;
    int gr = row0 + r;
    uint4 v = {0u,0u,0u,0u};
    if (gr < rowsReal) {
      if constexpr (AF32) {
        const float* s = Af + (size_t)(ridx ? ridx[gr] : gr)*strideA + c8*8;
        float4 f0 = *(const float4*)s;
        float4 f1 = *(const float4*)(s + 4);
        v.x = pk2(f0.x, f0.y); v.y = pk2(f0.z, f0.w);
        v.z = pk2(f1.x, f1.y); v.w = pk2(f1.z, f1.w);
      } else {
        v = *(const uint4*)(A + (size_t)gr*strideA + c8*8);
      }
    }
    *(uint4*)(&Asm[r*LDA + c8*8]) = v;
  }
  if constexpr (NEXP > 1) {
    for (int u = tid; u < 128*NEXP; u += 512) {
      int r = u / NEXP, e = u - r*NEXP;
      int a = (row0 + r)/DIV;
      coefsm[r*NEXP + e] = coefg[(size_t)a*NEXP + e];
    }
  }
  __syncthreads();

  const int lane = tid & 63, wid = tid >> 6;
  const int rg = wid & 3, cg = wid >> 2;
  const int rbase = rg*32;
  const int lrow = lane & 15, lkb = lane >> 4;

  short8 af[2][NK];
  #pragma unroll
  for (int rt = 0; rt < 2; ++rt)
    #pragma unroll
    for (int kc = 0; kc < NK; ++kc)
      af[rt][kc] = *(const short8*)(&Asm[(rbase + rt*16 + lrow)*LDA + kc*32 + lkb*8]);

  f32x4 acc[2][CTW];
  #pragma unroll
  for (int rt = 0; rt < 2; ++rt)
    #pragma unroll
    for (int ct = 0; ct < CTW; ++ct)
      acc[rt][ct] = f32x4{0.f,0.f,0.f,0.f};

  union BU { uint4 u; short8 s; };

  if constexpr (NEXP == 1) {
    #pragma unroll
    for (int ct = 0; ct < CTW; ++ct) {
      const ushort* bp = Bpk + ((size_t)(cg*CTW + ct)*NK*64 + lane)*8;
      #pragma unroll
      for (int kc = 0; kc < NK; ++kc) {
        BU b; b.u = *(const uint4*)(bp + (size_t)kc*512);
        acc[0][ct] = __builtin_amdgcn_mfma_f32_16x16x32_bf16(af[0][kc], b.s, acc[0][ct], 0, 0, 0);
        acc[1][ct] = __builtin_amdgcn_mfma_f32_16x16x32_bf16(af[1][kc], b.s, acc[1][ct], 0, 0, 0);
      }
    }
  } else {
    for (int e = 0; e < NEXP; ++e) {
      float cf[2][4];
      #pragma unroll
      for (int rt = 0; rt < 2; ++rt)
        #pragma unroll
        for (int q = 0; q < 4; ++q)
          cf[rt][q] = coefsm[(rbase + rt*16 + lkb*4 + q)*NEXP + e];
      #pragma unroll
      for (int ct = 0; ct < CTW; ++ct) {
        const ushort* bp = Bpk + ((size_t)((e*NT + cg*CTW + ct)*NK)*64 + lane)*8;
        f32x4 z0 = {0.f,0.f,0.f,0.f}, z1 = {0.f,0.f,0.f,0.f};
        #pragma unroll
        for (int kc = 0; kc < NK; ++kc) {
          BU b; b.u = *(const uint4*)(bp + (size_t)kc*512);
          z0 = __builtin_amdgcn_mfma_f32_16x16x32_bf16(af[0][kc], b.s, z0, 0, 0, 0);
          z1 = __builtin_amdgcn_mfma_f32_16x16x32_bf16(af[1][kc], b.s, z1, 0, 0, 0);
        }
        #pragma unroll
        for (int q = 0; q < 4; ++q) {
          acc[0][ct][q] += cf[0][q]*z0[q];
          acc[1][ct][q] += cf[1][q]*z1[q];
        }
      }
    }
  }

  #pragma unroll
  for (int rt = 0; rt < 2; ++rt) {
    #pragma unroll
    for (int ct = 0; ct < CTW; ++ct) {
      #pragma unroll
      for (int q = 0; q < 4; ++q) {
        int gr = row0 + rbase + rt*16 + lkb*4 + q;
        if (gr >= rowsReal) continue;
        int o = (cg*CTW + ct)*16 + lrow;
        float val = acc[rt][ct][q]*norm;
        if constexpr (EPI == 0) {
          outbf[(size_t)gr*N + o] = bf(val);
        } else if constexpr (EPI == 1) {
          float av = (o < 128) ? (val/(1.f + __expf(-val)))
                               : (1.f/(1.f + __expf(-val)));
          outbf[(size_t)gr*N + o] = bf(av);
        } else {
          int a = gr/DIV, n = gr - a*DIV;
          if (bias != nullptr) val += bias[o];
          float w = fb(wenvbf[(size_t)a*224 + WCOL + o]);
          val *= w*0.22360679774997896f;
          atomicAdd(accw + (size_t)cen[a]*kNFD + OB + o*DIV + n, val);
        }
      }
    }
  }
}

// ---------------------------------------------------------------------------
// Rotate-back + sigmoid gating (vectorized short8).
// ---------------------------------------------------------------------------
__global__ __launch_bounds__(256)
void mid_k(const ushort* __restrict__ y1, const ushort* __restrict__ y2,
           const ushort* __restrict__ t0act, const float* __restrict__ D1,
           const float* __restrict__ D2, ushort* __restrict__ v1,
           ushort* __restrict__ v2) {
  const int base = blockIdx.x*64;
  const int tid = threadIdx.x;

  // v1: 64 edges x 3 n-rows x 8 col-groups
  for (int u = tid; u < 64*24; u += 256) {
    int e = u/24, r = u - e*24;
    int n = r >> 3, g = r & 7;
    int c0 = g*8;
    size_t a = base + e;
    const float* dd = D1 + a*9 + n*3;
    float d0 = dd[0], d1 = dd[1], d2 = dd[2];
    short8 m0 = *(const short8*)(y1 + ((size_t)a*3 + 0)*64 + c0);
    short8 m1 = *(const short8*)(y1 + ((size_t)a*3 + 1)*64 + c0);
    short8 m2 = *(const short8*)(y1 + ((size_t)a*3 + 2)*64 + c0);
    short8 gt = *(const short8*)(t0act + a*224 + 128 + c0);
    float ov[8];
    #pragma unroll
    for (int j = 0; j < 8; ++j) {
      float s = d0*fb((ushort)m0[j]) + d1*fb((ushort)m1[j]) + d2*fb((ushort)m2[j]);
      ov[j] = s*fb((ushort)gt[j]);
    }
    uint4 o;
    o.x = pk2(ov[0], ov[1]); o.y = pk2(ov[2], ov[3]);
    o.z = pk2(ov[4], ov[5]); o.w = pk2(ov[6], ov[7]);
    *(uint4*)(v1 + ((size_t)a*3 + n)*64 + c0) = o;
  }

  // v2: 64 edges x 5 n-rows x 4 col-groups (32 cols)
  for (int u = tid; u < 64*20; u += 256) {
    int e = u/20, r = u - e*20;
    int n = r >> 2, g = r & 3;
    int c0 = g*8;
    size_t a = base + e;
    const float* dd = D2 + a*25 + n*5;
    short8 m0 = *(const short8*)(y2 + ((size_t)a*5 + 0)*32 + c0);
    short8 m1 = *(const short8*)(y2 + ((size_t)a*5 + 1)*32 + c0);
    short8 m2 = *(const short8*)(y2 + ((size_t)a*5 + 2)*32 + c0);
    short8 m3 = *(const short8*)(y2 + ((size_t)a*5 + 3)*32 + c0);
    short8 m4 = *(const short8*)(y2 + ((size_t)a*5 + 4)*32 + c0);
    short8 gt = *(const short8*)(t0act + a*224 + 192 + c0);
    float ov[8];
    #pragma unroll
    for (int j = 0; j < 8; ++j) {
      float s = dd[0]*fb((ushort)m0[j]) + dd[1]*fb((ushort)m1[j])
              + dd[2]*fb((ushort)m2[j]) + dd[3]*fb((ushort)m3[j])
              + dd[4]*fb((ushort)m4[j]);
      ov[j] = s*fb((ushort)gt[j]);
    }
    uint4 o;
    o.x = pk2(ov[0], ov[1]); o.y = pk2(ov[2], ov[3]);
    o.z = pk2(ov[4], ov[5]); o.w = pk2(ov[6], ov[7]);
    *(uint4*)(v2 + ((size_t)a*5 + n)*32 + c0) = o;
  }
}

// ---------------------------------------------------------------------------
// Node finalize (unchanged).
// ---------------------------------------------------------------------------
__global__ __launch_bounds__(256)
void node_k(const float* __restrict__ nodef, const float* __restrict__ onehot,
            const float* __restrict__ Woh0, const float* __restrict__ Woh1,
            const float* __restrict__ Woh2, const float* __restrict__ accw,
            float* __restrict__ out) {
  __shared__ int tn;
  const int n = blockIdx.x;
  const int t = threadIdx.x;
  if (t < kNT && onehot[(size_t)n*kNT + t] > 0.5f) tn = t;
  __syncthreads();
  const int ty = tn;
  const float c_old = 0.8944271909999159f;
  const float c_new = 0.4472135954999579f;
  const float invs  = 0.10259783520851541f;
  for (int j = t; j < kNFD; j += 256) {
    float h = c_old*nodef[(size_t)n*kNFD + j] + c_new*accw[(size_t)n*kNFD + j];
    float f;
    if (j < 128)      f = Woh0[j*kNT + ty];
    else if (j < 320) f = Woh1[((j - 128)/3)*kNT + ty];
    else              f = Woh2[((j - 320)/5)*kNT + ty];
    out[(size_t)n*kNFD + j] = h*(1.f + f*invs);
  }
}

// workspace layout (bytes)
constexpr size_t OFF_ACCW = 0;
constexpr size_t OFF_COEF = 19200000;
constexpr size_t OFF_CEN  = 26402304;
constexpr size_t OFF_X0   = 27202560;
constexpr size_t OFF_X1R  = 104027136;
constexpr size_t OFF_X2R  = 219264000;
constexpr size_t OFF_WENV = 347272192;
constexpr size_t OFF_T0A  = 436900864;
constexpr size_t OFF_Y1   = 526529536;
constexpr size_t OFF_Y2   = 603354112;
constexpr size_t OFF_PACK = 667358208;

} // namespace

extern "C" void kernel_launch(void* const* d_in, const int* in_sizes, int n_in,
                              void* d_out, int out_size, void* d_ws, size_t ws_size,
                              hipStream_t stream) {
  (void)in_sizes; (void)n_in; (void)out_size; (void)ws_size;
  const float* latents = (const float*)d_in[0];
  const float* nodef   = (const float*)d_in[1];
  const float* edgef   = (const float*)d_in[2];
  const float* mg      = (const float*)d_in[4];
  const float* D1      = (const float*)d_in[5];
  const float* D2      = (const float*)d_in[6];
  const float* onehot  = (const float*)d_in[7];
  const float* Wg      = (const float*)d_in[8];
  const float* Wm      = (const float*)d_in[9];
  const float* W0e     = (const float*)d_in[10];
  const float* W0s     = (const float*)d_in[11];
  const float* W1e     = (const float*)d_in[12];
  const float* W1s     = (const float*)d_in[13];
  const float* W2e     = (const float*)d_in[14];
  const float* W2s     = (const float*)d_in[15];
  const float* Wp0     = (const float*)d_in[16];
  const float* bp0     = (const float*)d_in[17];
  const float* Wp1     = (const float*)d_in[18];
  const float* Wp2     = (const float*)d_in[19];
  const float* Wenv    = (const float*)d_in[20];
  const float* Woh0    = (const float*)d_in[21];
  const float* Woh1    = (const float*)d_in[22];
  const float* Woh2    = (const float*)d_in[23];
  const int* eidx      = (const int*)d_in[25];
  const int* act       = (const int*)d_in[26];

  char* ws = (char*)d_ws;
  float*  accw  = (float*)(ws + OFF_ACCW);
  float*  coef  = (float*)(ws + OFF_COEF);
  int*    ceng  = (int*)(ws + OFF_CEN);
  ushort* x0    = (ushort*)(ws + OFF_X0);
  ushort* x1r   = (ushort*)(ws + OFF_X1R);
  ushort* x2r   = (ushort*)(ws + OFF_X2R);
  ushort* wenv  = (ushort*)(ws + OFF_WENV);
  ushort* t0act = (ushort*)(ws + OFF_T0A);
  ushort* y1    = (ushort*)(ws + OFF_Y1);
  ushort* y2    = (ushort*)(ws + OFF_Y2);
  ushort* v1    = (ushort*)(ws + OFF_X0);    // alias: x0 dead after G_t0
  ushort* v2    = (ushort*)(ws + OFF_X1R);   // alias: x1r dead after G_y1
  ushort* pk    = (ushort*)(ws + OFF_PACK);
  float*  out   = (float*)d_out;

  hipMemsetAsync(accw, 0, (size_t)kN*kNFD*sizeof(float), stream);

  pack_k<<<(PKTOT + 255)/256, 256, 0, stream>>>(W0e, W0s, W1e, W1s, W2e, W2s,
                                                Wenv, Wp0, Wp1, Wp2, pk);

  hipFuncSetAttribute((const void*)prep_k,
                      hipFuncAttributeMaxDynamicSharedMemorySize,
                      PSM_FLOATS*(int)sizeof(float));
  prep_k<<<kE/PEB, 512, PSM_FLOATS*sizeof(float), stream>>>(
      latents, nodef, edgef, mg, D1, D2, Wg, Wm,
      eidx, act, coef, ceng, x0, x1r, x2r);

  // t0 = mix0(x0) -> silu/sigmoid activations
  gemm_k<1,192,6,224,9,1,false><<<1563, 512, 0, stream>>>(
      x0, nullptr, nullptr, 192, pk + PK0, coef, kE, 0.07216878364870323f,
      t0act, nullptr, nullptr, nullptr, nullptr, 0, 0);
  // wenv = latents[act] @ Wenv / sqrt(128)
  gemm_k<1,128,4,224,1,0,true><<<1563, 512, 0, stream>>>(
      nullptr, latents, act, 128, pk + PKENV, nullptr, kE, 0.08838834764831845f,
      wenv, nullptr, nullptr, nullptr, nullptr, 0, 0);
  // y1 = mix1(x1r)
  gemm_k<3,96,3,64,9,0,false><<<4688, 512, 0, stream>>>(
      x1r, nullptr, nullptr, 96, pk + PK1, coef, 3*kE, 0.10206207261596577f,
      y1, nullptr, nullptr, nullptr, nullptr, 0, 0);
  // y2 = mix2(x2r)
  gemm_k<5,64,2,32,9,0,false><<<7813, 512, 0, stream>>>(
      x2r, nullptr, nullptr, 64, pk + PK2, coef, 5*kE, 0.14433756729740643f,
      y2, nullptr, nullptr, nullptr, nullptr, 0, 0);

  mid_k<<<kE/64, 256, 0, stream>>>(y1, y2, t0act, D1, D2, v1, v2);

  // P0: silu-part of t0act @ Wp0 -> atomic
  gemm_k<1,128,4,128,1,2,false><<<1563, 512, 0, stream>>>(
      t0act, nullptr, nullptr, 224, pk + PKP0, nullptr, kE, 0.08838834764831845f,
      nullptr, bp0, wenv, ceng, accw, 0, 0);
  // P1: v1 @ Wp1 -> atomic
  gemm_k<3,64,2,64,1,2,false><<<4688, 512, 0, stream>>>(
      v1, nullptr, nullptr, 64, pk + PKP1, nullptr, 3*kE, 0.125f,
      nullptr, nullptr, wenv, ceng, accw, 128, 128);
  // P2: v2 @ Wp2 -> atomic
  gemm_k<5,32,1,32,1,2,false><<<7813, 512, 0, stream>>>(
      v2, nullptr, nullptr, 32, pk + PKP2, nullptr, 5*kE, 0.17677669529663687f,
      nullptr, nullptr, wenv, ceng, accw, 192, 320);

  node_k<<<kN, 256, 0, stream>>>(nodef, onehot, Woh0, Woh1, Woh2, accw, out);
}